// Round 1
// baseline (1119.614 us; speedup 1.0000x reference)
//
#include <hip/hip_runtime.h>
#include <cstdint>

typedef unsigned short u16;
typedef __bf16 bf16x8 __attribute__((ext_vector_type(8)));
typedef float f32x4 __attribute__((ext_vector_type(4)));

#define M_TOT 8192      // B*S
#define D_IN  4096
#define Z_DIM 1024
#define D_OUT 4096
#define K_CAT 5120      // Z + D_IN

struct alignas(8) u16x4 { u16 x, y, z, w; };

__device__ __forceinline__ u16 to_bf16(float f) {
    union { float f; uint32_t u; } v; v.f = f;
    uint32_t u = v.u;
    // round-to-nearest-even
    uint32_t r = (u + 0x7FFFu + ((u >> 16) & 1u)) >> 16;
    return (u16)r;
}

__device__ __forceinline__ void async_load16(const void* g, void* l) {
    __builtin_amdgcn_global_load_lds(
        (const __attribute__((address_space(1))) void*)g,
        (__attribute__((address_space(3))) void*)l,
        16, 0, 0);
}

// ---------------------------------------------------------------------------
// GEMM: C[M,N] = A[M,K] (bf16) @ W[N,K]^T (bf16) + bias[N], fp32 out.
// 128x128 tile, BK=32, 256 threads (4 waves, 2x2 of 64x64), 16x16x32 bf16 MFMA.
// blockIdx.z selects {W,bias,C} set 0 or 1 (for fused mu/logsigma heads).
// M,N multiples of 128; K multiple of 32. No bounds checks.
// ---------------------------------------------------------------------------
__global__ __launch_bounds__(256)
void gemm_bt(const u16* __restrict__ A,
             const u16* __restrict__ Bw0, const u16* __restrict__ Bw1,
             const float* __restrict__ bias0, const float* __restrict__ bias1,
             float* __restrict__ C0, float* __restrict__ C1,
             int M, int N, int K)
{
    const u16*  Bw   = blockIdx.z ? Bw1   : Bw0;
    const float* bias = blockIdx.z ? bias1 : bias0;
    float*       C    = blockIdx.z ? C1    : C0;

    __shared__ u16 As[128 * 32];
    __shared__ u16 Bs[128 * 32];

    const int tid  = threadIdx.x;
    const int wave = tid >> 6;
    const int lane = tid & 63;
    const int m0 = blockIdx.y * 128;
    const int n0 = blockIdx.x * 128;
    const int wm = (wave & 1) * 64;
    const int wn = (wave >> 1) * 64;

    // staging: each wave fills 32 rows (two 16-row chunks of 1024B each).
    // lane l -> row (l>>2), k-col (l&3)*8 within chunk; LDS dst = base + lane*16B.
    const int srow = wave * 32 + (lane >> 2);
    const int scol = (lane & 3) * 8;
    const long long a_off = (long long)(m0 + srow) * K + scol;
    const long long b_off = (long long)(n0 + srow) * K + scol;

    const int fr = lane & 15;   // fragment row/col
    const int fq = lane >> 4;   // quad

    f32x4 acc[4][4] = {};

    for (int k0 = 0; k0 < K; k0 += 32) {
        async_load16(A  + a_off + k0,            &As[(wave * 32 +  0) * 32]);
        async_load16(A  + a_off + k0 + 16LL * K, &As[(wave * 32 + 16) * 32]);
        async_load16(Bw + b_off + k0,            &Bs[(wave * 32 +  0) * 32]);
        async_load16(Bw + b_off + k0 + 16LL * K, &Bs[(wave * 32 + 16) * 32]);
        __syncthreads();

        bf16x8 af[4], bf[4];
        #pragma unroll
        for (int i = 0; i < 4; i++)
            af[i] = *(const bf16x8*)&As[(wm + i * 16 + fr) * 32 + fq * 8];
        #pragma unroll
        for (int i = 0; i < 4; i++)
            bf[i] = *(const bf16x8*)&Bs[(wn + i * 16 + fr) * 32 + fq * 8];

        #pragma unroll
        for (int mi = 0; mi < 4; mi++)
            #pragma unroll
            for (int ni = 0; ni < 4; ni++)
                acc[mi][ni] = __builtin_amdgcn_mfma_f32_16x16x32_bf16(
                    af[mi], bf[ni], acc[mi][ni], 0, 0, 0);
        __syncthreads();
    }

    #pragma unroll
    for (int ni = 0; ni < 4; ni++) {
        const int col = n0 + wn + ni * 16 + fr;
        const float bv = bias[col];
        #pragma unroll
        for (int mi = 0; mi < 4; mi++) {
            const int row = m0 + wm + mi * 16 + fq * 4;
            float* cp = C + (long long)row * N + col;
            #pragma unroll
            for (int r = 0; r < 4; r++)
                cp[(long long)r * N] = acc[mi][ni][r] + bv;
        }
    }
}

// ---------------------------------------------------------------------------
// LayerNorm(z=1024) + tanh -> bf16. One 256-thread block per row.
// ---------------------------------------------------------------------------
__global__ __launch_bounds__(256)
void ln_tanh_kernel(const float* __restrict__ in, const float* __restrict__ g,
                    const float* __restrict__ be, u16* __restrict__ out)
{
    const int row = blockIdx.x;
    const int t = threadIdx.x;
    const float4 v = ((const float4*)(in + (long long)row * 1024))[t];
    float s  = v.x + v.y + v.z + v.w;
    float s2 = v.x * v.x + v.y * v.y + v.z * v.z + v.w * v.w;
    #pragma unroll
    for (int off = 32; off > 0; off >>= 1) {
        s  += __shfl_down(s,  off);
        s2 += __shfl_down(s2, off);
    }
    __shared__ float red[8];
    if ((t & 63) == 0) { red[t >> 6] = s; red[4 + (t >> 6)] = s2; }
    __syncthreads();
    s  = red[0] + red[1] + red[2] + red[3];
    s2 = red[4] + red[5] + red[6] + red[7];
    const float mean = s * (1.0f / 1024.0f);
    const float inv  = rsqrtf(s2 * (1.0f / 1024.0f) - mean * mean + 1e-5f);
    const float4 gg = ((const float4*)g)[t];
    const float4 bb = ((const float4*)be)[t];
    u16x4 o;
    o.x = to_bf16(tanhf((v.x - mean) * inv * gg.x + bb.x));
    o.y = to_bf16(tanhf((v.y - mean) * inv * gg.y + bb.y));
    o.z = to_bf16(tanhf((v.z - mean) * inv * gg.z + bb.z));
    o.w = to_bf16(tanhf((v.w - mean) * inv * gg.w + bb.w));
    ((u16x4*)(out + (long long)row * 1024))[t] = o;
}

// ---------------------------------------------------------------------------
// x prep: x fp32 -> x bf16 (GEMM1 A) and tanh(x) bf16 -> zc[:, 1024:5120].
// ---------------------------------------------------------------------------
__global__ __launch_bounds__(256)
void prep_x_kernel(const float* __restrict__ x, u16* __restrict__ xb,
                   u16* __restrict__ zc)
{
    const long long i = (long long)blockIdx.x * 256 + threadIdx.x;  // float4 index
    const float4 v = ((const float4*)x)[i];
    u16x4 b;
    b.x = to_bf16(v.x); b.y = to_bf16(v.y); b.z = to_bf16(v.z); b.w = to_bf16(v.w);
    ((u16x4*)xb)[i] = b;
    const long long flat = i * 4;
    const long long row = flat >> 12;        // / 4096
    const int col = (int)(flat & 4095);
    u16x4 tq;
    tq.x = to_bf16(tanhf(v.x)); tq.y = to_bf16(tanhf(v.y));
    tq.z = to_bf16(tanhf(v.z)); tq.w = to_bf16(tanhf(v.w));
    *(u16x4*)(zc + row * (long long)K_CAT + 1024 + col) = tq;
}

// ---------------------------------------------------------------------------
// Reparameterization: std = exp(0.5*ls) (overwrites ls slot in d_out),
// z = eps*std + mu, tanh(z) bf16 -> zc[:, 0:1024]. One block per row.
// ---------------------------------------------------------------------------
__global__ __launch_bounds__(256)
void reparam_kernel(const float* __restrict__ mu, float* __restrict__ lsstd,
                    const float* __restrict__ eps, u16* __restrict__ zc)
{
    const long long row = blockIdx.x;
    const int c = threadIdx.x * 4;
    const long long idx = row * 1024 + c;
    const float4 m = *(const float4*)(mu + idx);
    const float4 l = *(const float4*)(lsstd + idx);
    const float4 e = *(const float4*)(eps + idx);
    float4 sd;
    sd.x = expf(0.5f * l.x); sd.y = expf(0.5f * l.y);
    sd.z = expf(0.5f * l.z); sd.w = expf(0.5f * l.w);
    *(float4*)(lsstd + idx) = sd;
    u16x4 t;
    t.x = to_bf16(tanhf(e.x * sd.x + m.x));
    t.y = to_bf16(tanhf(e.y * sd.y + m.y));
    t.z = to_bf16(tanhf(e.z * sd.z + m.z));
    t.w = to_bf16(tanhf(e.w * sd.w + m.w));
    *(u16x4*)(zc + row * (long long)K_CAT + c) = t;
}

// fp32 -> bf16 bulk convert (n4 = count of float4 quads)
__global__ __launch_bounds__(256)
void cvt_kernel(const float* __restrict__ src, u16* __restrict__ dst, long long n4)
{
    const long long i = (long long)blockIdx.x * 256 + threadIdx.x;
    if (i >= n4) return;
    const float4 v = ((const float4*)src)[i];
    u16x4 b;
    b.x = to_bf16(v.x); b.y = to_bf16(v.y); b.z = to_bf16(v.z); b.w = to_bf16(v.w);
    ((u16x4*)dst)[i] = b;
}

extern "C" void kernel_launch(void* const* d_in, const int* in_sizes, int n_in,
                              void* d_out, int out_size, void* d_ws, size_t ws_size,
                              hipStream_t stream)
{
    const float* x   = (const float*)d_in[0];
    const float* eps = (const float*)d_in[1];
    const float* W1  = (const float*)d_in[2];
    const float* b1  = (const float*)d_in[3];
    const float* g1  = (const float*)d_in[4];
    const float* be1 = (const float*)d_in[5];
    const float* W2  = (const float*)d_in[6];
    const float* b2  = (const float*)d_in[7];
    const float* g2  = (const float*)d_in[8];
    const float* be2 = (const float*)d_in[9];
    const float* Wmu = (const float*)d_in[10];
    const float* bmu = (const float*)d_in[11];
    const float* Wls = (const float*)d_in[12];
    const float* bls = (const float*)d_in[13];
    const float* Wzw = (const float*)d_in[14];
    const float* bzw = (const float*)d_in[15];

    float* out  = (float*)d_out;                         // [8192,4096]
    float* mu   = out + (long long)M_TOT * D_OUT;        // [8192,1024]
    float* std_ = mu  + (long long)M_TOT * Z_DIM;        // [8192,1024]

    // workspace layout (bytes):
    char* ws = (char*)d_ws;
    u16*   xb   = (u16*)(ws);                  //  67,108,864  x bf16 [8192,4096]
    u16*   zc   = (u16*)(ws +  67108864);      //  83,886,080  concat bf16 [8192,5120]
    u16*   h1   = (u16*)(ws + 150994944);      //  16,777,216
    u16*   h2   = (u16*)(ws + 167772160);      //  16,777,216
    float* pre  = (float*)(ws + 184549376);    //  33,554,432  GEMM fp32 out [8192,1024]
    u16*   W1b  = (u16*)(ws + 218103808);      //   8,388,608
    u16*   W2b  = (u16*)(ws + 226492416);      //   2,097,152
    u16*   Wmub = (u16*)(ws + 228589568);      //   2,097,152
    u16*   Wlsb = (u16*)(ws + 230686720);      //   2,097,152
    u16*   Wzwb = (u16*)(ws);                  // reuses xb region after GEMM1 (42MB<=64MB)
    // total ws = 232,783,872 bytes

    // weight conversions (stream-ordered)
    cvt_kernel<<<4096, 256, 0, stream>>>(W1,  W1b,  1048576);
    cvt_kernel<<<1024, 256, 0, stream>>>(W2,  W2b,   262144);
    cvt_kernel<<<1024, 256, 0, stream>>>(Wmu, Wmub,  262144);
    cvt_kernel<<<1024, 256, 0, stream>>>(Wls, Wlsb,  262144);

    // x -> bf16 + tanh(x) into concat buffer right half
    prep_x_kernel<<<32768, 256, 0, stream>>>(x, xb, zc);

    // layer 1: pre = x @ W1^T + b1 ; h1 = tanh(LN(pre))
    gemm_bt<<<dim3(8, 64, 1), 256, 0, stream>>>(xb, W1b, W1b, b1, b1, pre, pre,
                                                M_TOT, Z_DIM, D_IN);
    ln_tanh_kernel<<<8192, 256, 0, stream>>>(pre, g1, be1, h1);

    // Wzw conversion AFTER gemm1 (Wzwb aliases xb)
    cvt_kernel<<<20480, 256, 0, stream>>>(Wzw, Wzwb, 5242880);

    // layer 2
    gemm_bt<<<dim3(8, 64, 1), 256, 0, stream>>>(h1, W2b, W2b, b2, b2, pre, pre,
                                                M_TOT, Z_DIM, Z_DIM);
    ln_tanh_kernel<<<8192, 256, 0, stream>>>(pre, g2, be2, h2);

    // mu / logsigma heads (dual GEMM via gridDim.z)
    gemm_bt<<<dim3(8, 64, 2), 256, 0, stream>>>(h2, Wmub, Wlsb, bmu, bls, mu, std_,
                                                M_TOT, Z_DIM, Z_DIM);

    // reparameterize: std (into d_out), tanh(z) -> concat left half
    reparam_kernel<<<8192, 256, 0, stream>>>(mu, std_, eps, zc);

    // final projection: out = tanh([z,x]) @ Wzw^T + bzw
    gemm_bt<<<dim3(32, 64, 1), 256, 0, stream>>>(zc, Wzwb, Wzwb, bzw, bzw, out, out,
                                                 M_TOT, D_OUT, K_CAT);
}

// Round 2
// 1094.378 us; speedup vs baseline: 1.0231x; 1.0231x over previous
//
#include <hip/hip_runtime.h>
#include <cstdint>

typedef unsigned short u16;
typedef __bf16 bf16x8 __attribute__((ext_vector_type(8)));
typedef float f32x4 __attribute__((ext_vector_type(4)));

#define M_TOT 8192      // B*S
#define D_IN  4096
#define Z_DIM 1024
#define D_OUT 4096
#define K_CAT 5120      // Z + D_IN

struct alignas(8) u16x4 { u16 x, y, z, w; };

__device__ __forceinline__ u16 to_bf16(float f) {
    union { float f; uint32_t u; } v; v.f = f;
    uint32_t u = v.u;
    // round-to-nearest-even
    uint32_t r = (u + 0x7FFFu + ((u >> 16) & 1u)) >> 16;
    return (u16)r;
}

__device__ __forceinline__ void async_load16(const void* g, void* l) {
    __builtin_amdgcn_global_load_lds(
        (const __attribute__((address_space(1))) void*)g,
        (__attribute__((address_space(3))) void*)l,
        16, 0, 0);
}

// ---------------------------------------------------------------------------
// GEMM: C[M,N] = A[M,K] (bf16) @ W[N,K]^T (bf16) + bias[N], fp32 out.
// 128x128 tile, BK=32, 256 threads (4 waves, 2x2 of 64x64), 16x16x32 bf16 MFMA.
// LDS XOR swizzle: 16B chunk c of row r stored at chunk position c ^ ((r>>1)&3)
// -> fragment ds_read_b128 is 2-way-aliased only (free), vs 8-way unswizzled.
// blockIdx.z selects {W,bias,C} set 0 or 1 (for fused mu/logsigma heads).
// M,N multiples of 128; K multiple of 32. No bounds checks.
// ---------------------------------------------------------------------------
__global__ __launch_bounds__(256)
void gemm_bt(const u16* __restrict__ A,
             const u16* __restrict__ Bw0, const u16* __restrict__ Bw1,
             const float* __restrict__ bias0, const float* __restrict__ bias1,
             float* __restrict__ C0, float* __restrict__ C1,
             int M, int N, int K)
{
    const u16*  Bw   = blockIdx.z ? Bw1   : Bw0;
    const float* bias = blockIdx.z ? bias1 : bias0;
    float*       C    = blockIdx.z ? C1    : C0;

    __shared__ u16 As[128 * 32];
    __shared__ u16 Bs[128 * 32];

    const int tid  = threadIdx.x;
    const int wave = tid >> 6;
    const int lane = tid & 63;
    const int m0 = blockIdx.y * 128;
    const int n0 = blockIdx.x * 128;
    const int wm = (wave & 1) * 64;
    const int wn = (wave >> 1) * 64;

    // staging: each wave fills 32 rows (two 16-row chunks of 1024B each).
    // lane l -> row (l>>2); global k-chunk is XOR-swizzled so that LDS
    // position (l&3) holds chunk (l&3)^((srow>>1)&3). Row+16 has the same
    // swizzle factor ((r+16)>>1 ≡ r>>1 mod 4), so one scol serves both.
    const int srow = wave * 32 + (lane >> 2);
    const int scol = (((lane & 3) ^ ((srow >> 1) & 3))) * 8;
    const long long a_off = (long long)(m0 + srow) * K + scol;
    const long long b_off = (long long)(n0 + srow) * K + scol;

    const int fr = lane & 15;   // fragment row/col
    const int fq = lane >> 4;   // quad
    // reader-side swizzled chunk offset: (wm+i*16+fr)>>1 & 3 == (fr>>1)&3
    const int rc = (fq ^ ((fr >> 1) & 3)) * 8;

    f32x4 acc[4][4] = {};

    for (int k0 = 0; k0 < K; k0 += 32) {
        async_load16(A  + a_off + k0,            &As[(wave * 32 +  0) * 32]);
        async_load16(A  + a_off + k0 + 16LL * K, &As[(wave * 32 + 16) * 32]);
        async_load16(Bw + b_off + k0,            &Bs[(wave * 32 +  0) * 32]);
        async_load16(Bw + b_off + k0 + 16LL * K, &Bs[(wave * 32 + 16) * 32]);
        __syncthreads();

        bf16x8 af[4], bf[4];
        #pragma unroll
        for (int i = 0; i < 4; i++)
            af[i] = *(const bf16x8*)&As[(wm + i * 16 + fr) * 32 + rc];
        #pragma unroll
        for (int i = 0; i < 4; i++)
            bf[i] = *(const bf16x8*)&Bs[(wn + i * 16 + fr) * 32 + rc];

        #pragma unroll
        for (int mi = 0; mi < 4; mi++)
            #pragma unroll
            for (int ni = 0; ni < 4; ni++)
                acc[mi][ni] = __builtin_amdgcn_mfma_f32_16x16x32_bf16(
                    af[mi], bf[ni], acc[mi][ni], 0, 0, 0);
        __syncthreads();
    }

    #pragma unroll
    for (int ni = 0; ni < 4; ni++) {
        const int col = n0 + wn + ni * 16 + fr;
        const float bv = bias[col];
        #pragma unroll
        for (int mi = 0; mi < 4; mi++) {
            const int row = m0 + wm + mi * 16 + fq * 4;
            float* cp = C + (long long)row * N + col;
            #pragma unroll
            for (int r = 0; r < 4; r++)
                cp[(long long)r * N] = acc[mi][ni][r] + bv;
        }
    }
}

// ---------------------------------------------------------------------------
// LayerNorm(z=1024) + tanh -> bf16. One 256-thread block per row.
// ---------------------------------------------------------------------------
__global__ __launch_bounds__(256)
void ln_tanh_kernel(const float* __restrict__ in, const float* __restrict__ g,
                    const float* __restrict__ be, u16* __restrict__ out)
{
    const int row = blockIdx.x;
    const int t = threadIdx.x;
    const float4 v = ((const float4*)(in + (long long)row * 1024))[t];
    float s  = v.x + v.y + v.z + v.w;
    float s2 = v.x * v.x + v.y * v.y + v.z * v.z + v.w * v.w;
    #pragma unroll
    for (int off = 32; off > 0; off >>= 1) {
        s  += __shfl_down(s,  off);
        s2 += __shfl_down(s2, off);
    }
    __shared__ float red[8];
    if ((t & 63) == 0) { red[t >> 6] = s; red[4 + (t >> 6)] = s2; }
    __syncthreads();
    s  = red[0] + red[1] + red[2] + red[3];
    s2 = red[4] + red[5] + red[6] + red[7];
    const float mean = s * (1.0f / 1024.0f);
    const float inv  = rsqrtf(s2 * (1.0f / 1024.0f) - mean * mean + 1e-5f);
    const float4 gg = ((const float4*)g)[t];
    const float4 bb = ((const float4*)be)[t];
    u16x4 o;
    o.x = to_bf16(tanhf((v.x - mean) * inv * gg.x + bb.x));
    o.y = to_bf16(tanhf((v.y - mean) * inv * gg.y + bb.y));
    o.z = to_bf16(tanhf((v.z - mean) * inv * gg.z + bb.z));
    o.w = to_bf16(tanhf((v.w - mean) * inv * gg.w + bb.w));
    ((u16x4*)(out + (long long)row * 1024))[t] = o;
}

// ---------------------------------------------------------------------------
// x prep: x fp32 -> x bf16 (GEMM1 A) and tanh(x) bf16 -> zc[:, 1024:5120].
// ---------------------------------------------------------------------------
__global__ __launch_bounds__(256)
void prep_x_kernel(const float* __restrict__ x, u16* __restrict__ xb,
                   u16* __restrict__ zc)
{
    const long long i = (long long)blockIdx.x * 256 + threadIdx.x;  // float4 index
    const float4 v = ((const float4*)x)[i];
    u16x4 b;
    b.x = to_bf16(v.x); b.y = to_bf16(v.y); b.z = to_bf16(v.z); b.w = to_bf16(v.w);
    ((u16x4*)xb)[i] = b;
    const long long flat = i * 4;
    const long long row = flat >> 12;        // / 4096
    const int col = (int)(flat & 4095);
    u16x4 tq;
    tq.x = to_bf16(tanhf(v.x)); tq.y = to_bf16(tanhf(v.y));
    tq.z = to_bf16(tanhf(v.z)); tq.w = to_bf16(tanhf(v.w));
    *(u16x4*)(zc + row * (long long)K_CAT + 1024 + col) = tq;
}

// ---------------------------------------------------------------------------
// Reparameterization: std = exp(0.5*ls) (overwrites ls slot in d_out),
// z = eps*std + mu, tanh(z) bf16 -> zc[:, 0:1024]. One block per row.
// ---------------------------------------------------------------------------
__global__ __launch_bounds__(256)
void reparam_kernel(const float* __restrict__ mu, float* __restrict__ lsstd,
                    const float* __restrict__ eps, u16* __restrict__ zc)
{
    const long long row = blockIdx.x;
    const int c = threadIdx.x * 4;
    const long long idx = row * 1024 + c;
    const float4 m = *(const float4*)(mu + idx);
    const float4 l = *(const float4*)(lsstd + idx);
    const float4 e = *(const float4*)(eps + idx);
    float4 sd;
    sd.x = expf(0.5f * l.x); sd.y = expf(0.5f * l.y);
    sd.z = expf(0.5f * l.z); sd.w = expf(0.5f * l.w);
    *(float4*)(lsstd + idx) = sd;
    u16x4 t;
    t.x = to_bf16(tanhf(e.x * sd.x + m.x));
    t.y = to_bf16(tanhf(e.y * sd.y + m.y));
    t.z = to_bf16(tanhf(e.z * sd.z + m.z));
    t.w = to_bf16(tanhf(e.w * sd.w + m.w));
    *(u16x4*)(zc + row * (long long)K_CAT + c) = t;
}

// fp32 -> bf16 bulk convert (n4 = count of float4 quads)
__global__ __launch_bounds__(256)
void cvt_kernel(const float* __restrict__ src, u16* __restrict__ dst, long long n4)
{
    const long long i = (long long)blockIdx.x * 256 + threadIdx.x;
    if (i >= n4) return;
    const float4 v = ((const float4*)src)[i];
    u16x4 b;
    b.x = to_bf16(v.x); b.y = to_bf16(v.y); b.z = to_bf16(v.z); b.w = to_bf16(v.w);
    ((u16x4*)dst)[i] = b;
}

extern "C" void kernel_launch(void* const* d_in, const int* in_sizes, int n_in,
                              void* d_out, int out_size, void* d_ws, size_t ws_size,
                              hipStream_t stream)
{
    const float* x   = (const float*)d_in[0];
    const float* eps = (const float*)d_in[1];
    const float* W1  = (const float*)d_in[2];
    const float* b1  = (const float*)d_in[3];
    const float* g1  = (const float*)d_in[4];
    const float* be1 = (const float*)d_in[5];
    const float* W2  = (const float*)d_in[6];
    const float* b2  = (const float*)d_in[7];
    const float* g2  = (const float*)d_in[8];
    const float* be2 = (const float*)d_in[9];
    const float* Wmu = (const float*)d_in[10];
    const float* bmu = (const float*)d_in[11];
    const float* Wls = (const float*)d_in[12];
    const float* bls = (const float*)d_in[13];
    const float* Wzw = (const float*)d_in[14];
    const float* bzw = (const float*)d_in[15];

    float* out  = (float*)d_out;                         // [8192,4096]
    float* mu   = out + (long long)M_TOT * D_OUT;        // [8192,1024]
    float* std_ = mu  + (long long)M_TOT * Z_DIM;        // [8192,1024]

    // workspace layout (bytes):
    char* ws = (char*)d_ws;
    u16*   xb   = (u16*)(ws);                  //  67,108,864  x bf16 [8192,4096]
    u16*   zc   = (u16*)(ws +  67108864);      //  83,886,080  concat bf16 [8192,5120]
    u16*   h1   = (u16*)(ws + 150994944);      //  16,777,216
    u16*   h2   = (u16*)(ws + 167772160);      //  16,777,216
    float* pre  = (float*)(ws + 184549376);    //  33,554,432  GEMM fp32 out [8192,1024]
    u16*   W1b  = (u16*)(ws + 218103808);      //   8,388,608
    u16*   W2b  = (u16*)(ws + 226492416);      //   2,097,152
    u16*   Wmub = (u16*)(ws + 228589568);      //   2,097,152
    u16*   Wlsb = (u16*)(ws + 230686720);      //   2,097,152
    u16*   Wzwb = (u16*)(ws);                  // reuses xb region after GEMM1 (42MB<=64MB)
    // total ws = 232,783,872 bytes

    // weight conversions (stream-ordered)
    cvt_kernel<<<4096, 256, 0, stream>>>(W1,  W1b,  1048576);
    cvt_kernel<<<1024, 256, 0, stream>>>(W2,  W2b,   262144);
    cvt_kernel<<<1024, 256, 0, stream>>>(Wmu, Wmub,  262144);
    cvt_kernel<<<1024, 256, 0, stream>>>(Wls, Wlsb,  262144);

    // x -> bf16 + tanh(x) into concat buffer right half
    prep_x_kernel<<<32768, 256, 0, stream>>>(x, xb, zc);

    // layer 1: pre = x @ W1^T + b1 ; h1 = tanh(LN(pre))
    gemm_bt<<<dim3(8, 64, 1), 256, 0, stream>>>(xb, W1b, W1b, b1, b1, pre, pre,
                                                M_TOT, Z_DIM, D_IN);
    ln_tanh_kernel<<<8192, 256, 0, stream>>>(pre, g1, be1, h1);

    // Wzw conversion AFTER gemm1 (Wzwb aliases xb)
    cvt_kernel<<<20480, 256, 0, stream>>>(Wzw, Wzwb, 5242880);

    // layer 2
    gemm_bt<<<dim3(8, 64, 1), 256, 0, stream>>>(h1, W2b, W2b, b2, b2, pre, pre,
                                                M_TOT, Z_DIM, Z_DIM);
    ln_tanh_kernel<<<8192, 256, 0, stream>>>(pre, g2, be2, h2);

    // mu / logsigma heads (dual GEMM via gridDim.z)
    gemm_bt<<<dim3(8, 64, 2), 256, 0, stream>>>(h2, Wmub, Wlsb, bmu, bls, mu, std_,
                                                M_TOT, Z_DIM, Z_DIM);

    // reparameterize: std (into d_out), tanh(z) -> concat left half
    reparam_kernel<<<8192, 256, 0, stream>>>(mu, std_, eps, zc);

    // final projection: out = tanh([z,x]) @ Wzw^T + bzw
    gemm_bt<<<dim3(32, 64, 1), 256, 0, stream>>>(zc, Wzwb, Wzwb, bzw, bzw, out, out,
                                                 M_TOT, D_OUT, K_CAT);
}